// Round 6
// baseline (244.142 us; speedup 1.0000x reference)
//
#include <hip/hip_runtime.h>
#include <hip/hip_fp16.h>

// GCN 2-layer, N=100000, F=64, H=128, O=100, out [N,1] fp32.
// out = agg(relu(agg(x)@W1 + b1) . (W2@Wl)) + (b2@Wl + bl)
// Pipeline (r6):
//  prep:    pack W1 (fp16 hi+lo), v=W2@Wl, c=b2.Wl+bl, init 12512 bin cursors.
//  scatter: per edge, ONE global atomicAdd on bin (bucket=dst>>7, tile=src>>13,
//           cap 256 = mean+7sigma) + scattered 4B payload write into buf.
//           Replaces the old LDS-multisplit partA (scan eliminated).
//  compact: per bucket: read its 16 bins (16KB) to regs, dl-histogram -> dinv,
//           overwrite the SAME region with int16 (2^12) dinv-prescaled y rows
//           (bins and y are bucket-aligned & equal-sized -> zero extra ws),
//           write packed tile-major csr. Replaces partB's LDS sort.
//  fused1:  782-block all-resident grid (4 blocks/CU); tile-order gather keeps
//           the live 1MB y-tile L2-hot per XCD (verified r4/r5: 60-64MB fetch);
//           2-chunk-deep gather pipeline (16 rows in flight/wave); int16 sext
//           -> native ds_add_u32 into stride-77 LDS (13*dl mod 32 spans all 32
//           banks -> ~2-way, free). MFMA + fused layer-2-weight epilogue.
//  out:     per-bucket tile-major zz gather + native int LDS accumulate.
// fp32 LDS atomicAdd is a ~440cyc CAS loop on this toolchain (rounds 1-3);
// everything accumulates in int fixed-point (native ds_add_u32).

#define N_NODES 100000
#define F_IN 64
#define HID 128
#define OUT2 100
#define BSHIFT 7
#define BNODES 128
#define NBUCKETS ((N_NODES + BNODES - 1) / BNODES)  // 782
#define SCAP 2560   // packed bucket capacity: mean 2046 + ~11 sigma
#define ACHUNK 4096 // edges per scatter block
#define SENTE 0xFFFFFFFFu
#define TSHIFT 13   // src tile = src >> 13 (8192 srcs = 1 MB of y per tile)
#define NTILES 13   // ceil(100000 / 8192)
#define TCAP 256    // per-(bucket,tile) bin capacity: mean 168 + 7 sigma
#define NBINS (NBUCKETS * 16)   // 12512 (tiles padded to 16 for shift indexing)
#define RSTRIDE 77  // acci ints per node row: odd -> 13*dl mod 32 spans 32 banks
#define YSCALE 4096.0f        // y int16 fixed-point 2^12
#define YINV   (1.0f / 4096.0f)
#define ZSCALE 8192.0f        // zz accumulation fixed-point 2^13
#define ZINV   (1.0f / 8192.0f)

typedef _Float16 half8 __attribute__((ext_vector_type(8)));
typedef float f32x4 __attribute__((ext_vector_type(4)));

static __device__ __forceinline__ half8 as_half8(uint4 u) {
    union { uint4 u; half8 h; } x; x.u = u; return x.h;
}

// Blocks 0..7: pack W1 (MFMA B-layout, fp16 hi+lo).
// Block 8: v = W2@Wl, c = b2.Wl + bl, init bin cursors bcur2[i] = i*TCAP.
__global__ __launch_bounds__(256) void prep_kernel(
    const float* __restrict__ W1, const float* __restrict__ W2,
    const float* __restrict__ b2, const float* __restrict__ Wl,
    const float* __restrict__ bl,
    float* __restrict__ v, float* __restrict__ c, uint4* __restrict__ Wpk,
    int* __restrict__ bcur2) {
    int t = threadIdx.x;
    if (blockIdx.x < 8) {
        // idx: bit10 = part (0=hi,1=lo), bits9..7 = cb, bit6 = kf, bits5..0 = lane
        int idx = blockIdx.x * 256 + t;
        int lane2 = idx & 63;
        int kf    = (idx >> 6) & 1;
        int cb    = (idx >> 7) & 7;
        int part  = (idx >> 10) & 1;
        union { uint4 u; unsigned short s[8]; } pk;
        #pragma unroll
        for (int j = 0; j < 8; ++j) {
            int k    = kf * 32 + (lane2 >> 4) * 8 + j;
            int colg = cb * 16 + (lane2 & 15);
            float w = W1[k * HID + colg];
            __half h = __float2half_rn(w);
            if (part) h = __float2half_rn(w - __half2float(h));
            pk.s[j] = __half_as_ushort(h);
        }
        Wpk[idx] = pk.u;
    } else {
        for (int i = t; i < NBINS; i += 256) bcur2[i] = i << 8;  // i*TCAP
        if (t < HID) {
            float acc = 0.f;
            for (int k = 0; k < OUT2; ++k) acc += W2[t * OUT2 + k] * Wl[k];
            v[t] = acc;
        } else if (t == HID) {
            float acc = bl[0];
            for (int k = 0; k < OUT2; ++k) acc += b2[k] * Wl[k];
            *c = acc;
        }
    }
}

// Scatter: per edge one global bin-atomic + one 4B payload write.
// bin = (dst>>7)*16 + (src>>13); payload = (src<<7)|(dst&127).
__global__ __launch_bounds__(256) void scatter_kernel(
    const int* __restrict__ src, const int* __restrict__ dst,
    int* __restrict__ bcur2, int* __restrict__ buf, int E) {
    int t = threadIdx.x;
    int base = blockIdx.x * ACHUNK;
    #pragma unroll
    for (int k = 0; k < 16; ++k) {
        int e = base + k * 256 + t;
        if (e < E) {
            int s = src[e], d = dst[e];
            int bin = ((d >> BSHIFT) << 4) | (s >> TSHIFT);
            int pos = atomicAdd(&bcur2[bin], 1);
            buf[pos] = (s << BSHIFT) | (d & (BNODES - 1));
        }
    }
}

// Compact: per bucket: bins -> regs, dl-histogram -> dinv, overwrite region
// with int16 y rows, write packed tile-major csr + bcnt.
__global__ __launch_bounds__(256) void compact_kernel(
    const int* __restrict__ bcur2, int* __restrict__ buf,
    unsigned int* __restrict__ csrP, int* __restrict__ bcnt,
    float* __restrict__ dinv, const float4* __restrict__ x4, int n) {
    __shared__ int scnt[16];
    __shared__ int soff[16];
    __shared__ int lcnt[BNODES];
    __shared__ float sdinv[BNODES];
    int b = blockIdx.x, t = threadIdx.x;
    int node0 = b << BSHIFT;
    int nlocal = min(BNODES, n - node0);
    int binbase = b << 12;            // *4096 ints (16 bins x 256)
    if (t < 16) scnt[t] = bcur2[(b << 4) | t] - (((b << 4) | t) << 8);
    if (t < BNODES) lcnt[t] = 0;
    __syncthreads();
    // read all 16 bin slots for this thread (garbage beyond scnt, masked below)
    int er[16];
    #pragma unroll
    for (int i = 0; i < 16; ++i) er[i] = buf[binbase + (i << 8) + t];
    // dl histogram over valid entries
    #pragma unroll
    for (int i = 0; i < NTILES; ++i)
        if (t < scnt[i]) atomicAdd(&lcnt[er[i] & (BNODES - 1)], 1);
    // keep ALL er loads live (region is overwritten by y below; the barrier's
    // vmcnt(0) then guarantees every thread's loads completed first)
    #pragma unroll
    for (int i = 0; i < 16; ++i) asm volatile("" :: "v"(er[i]));
    __syncthreads();
    if (t < BNODES) {
        float sd = rsqrtf((float)lcnt[t] + 1.0f);
        sdinv[t] = sd;
        if (t < nlocal) dinv[node0 + t] = sd;
    }
    if (t == 0) {
        int s = 0;
        #pragma unroll
        for (int i = 0; i < NTILES; ++i) {
            soff[i] = s;
            s += min(scnt[i], TCAP);
        }
        soff[NTILES] = s;
    }
    __syncthreads();
    // y emission: int16 fixed-point, dinv[src]-prescaled (overwrites bin region)
    uint2* y2 = (uint2*)buf;
    for (int i = t; i < nlocal * 16; i += 256) {
        int nl = i >> 4;
        int gi = (node0 + nl) * 16 + (i & 15);
        float sc = sdinv[nl] * YSCALE;
        float4 xv = x4[gi];
        int a0 = __float2int_rn(xv.x * sc);
        int a1 = __float2int_rn(xv.y * sc);
        int a2 = __float2int_rn(xv.z * sc);
        int a3 = __float2int_rn(xv.w * sc);
        uint2 pk;
        pk.x = ((unsigned int)a0 & 0xFFFFu) | ((unsigned int)a1 << 16);
        pk.y = ((unsigned int)a2 & 0xFFFFu) | ((unsigned int)a3 << 16);
        y2[gi] = pk;
    }
    // packed tile-major csr (from registers)
    int base2 = b * SCAP;
    #pragma unroll
    for (int i = 0; i < NTILES; ++i)
        if (t < scnt[i]) csrP[base2 + soff[i] + t] = (unsigned int)er[i];
    if (t == 0) bcnt[b] = soff[NTILES];
}

// Fused layer 1: block = bucket (128 dst nodes), 782 blocks, 4/CU all resident.
// csr is tile-major -> live 1MB y-tile stays L2-hot per XCD.
// Gather: 64 lanes = 8 edges (q=lane>>3) x 8 int4 cols (col=lane&7); 2 chunks
// software-pipelined (16 rows in flight/wave). int16 sext -> ds_add_u32 into
// stride-77 acci: bank = (13dl+9col+j)&31, dl spans all 32 banks -> ~2-way.
#define F1_ISSUE(EE, U, DL)                                            \
    _Pragma("unroll")                                                  \
    for (int g = 0; g < 8; ++g) {                                      \
        unsigned int e_ = __shfl((EE), g * 8 + q, 64);                 \
        bool valid_ = (e_ != SENTE);                                   \
        int srow_ = valid_ ? (int)(e_ >> BSHIFT) : 0;                  \
        DL[g] = (int)(e_ & (BNODES - 1));                              \
        U[g] = y4[srow_ * 8 + col];                                    \
        if (!valid_) U[g] = (int4){0, 0, 0, 0};                        \
    }

#define F1_CONSUME(U, DL)                                              \
    _Pragma("unroll")                                                  \
    for (int g = 0; g < 8; ++g) {                                      \
        int* rowp_ = &acci[DL[g] * RSTRIDE + col * 9];                 \
        const int* up_ = (const int*)&U[g];                            \
        _Pragma("unroll")                                              \
        for (int j = 0; j < 4; ++j) {                                  \
            int d_ = up_[j];                                           \
            atomicAdd(&rowp_[2 * j],     (d_ << 16) >> 16);            \
            atomicAdd(&rowp_[2 * j + 1], d_ >> 16);                    \
        }                                                              \
    }

__global__ __launch_bounds__(256, 4) void fused1_kernel(
    const int4* __restrict__ y4, const short* __restrict__ yh,
    const unsigned int* __restrict__ csrP, const int* __restrict__ bcnt,
    const float* __restrict__ dinv, const uint4* __restrict__ Wpk,
    const float* __restrict__ b1, const float* __restrict__ v,
    float* __restrict__ zz, int n) {
    __shared__ int acci[BNODES * RSTRIDE];   // 39424 B -> 4 blocks/CU
    int t = threadIdx.x;
    int lane = t & 63, wave = t >> 6;
    int q = lane >> 3, col = lane & 7;
    int b = blockIdx.x;
    int node0 = b << BSHIFT;
    int nlocal = min(BNODES, n - node0);
    int base = b * SCAP;
    int cnt = bcnt[b];

    // self-loop init: acc[r][f] = y[node0+r][f] (int16, already dinv-prescaled)
    for (int r = wave; r < BNODES; r += 4) {
        int vv = 0;
        if (r < nlocal) vv = (int)yh[(node0 + r) * 64 + lane];
        acci[r * RSTRIDE + (lane >> 3) * 9 + (lane & 7)] = vv;
    }
    __syncthreads();

    // 2-deep pipelined edge accumulation in tile order
    int nr = (cnt + 255) >> 8;
    int lpos = wave * 64 + lane;
    unsigned int eeA = (lpos < cnt) ? csrP[base + lpos] : SENTE;
    int4 uA[8]; int dlA[8];
    F1_ISSUE(eeA, uA, dlA);
    unsigned int eeB = (lpos + 256 < cnt) ? csrP[base + lpos + 256] : SENTE;
    #pragma unroll 2
    for (int r = 0; r < nr; ++r) {
        int4 uN[8]; int dlN[8];
        F1_ISSUE(eeB, uN, dlN);                 // chunk r+1 (sentinel-safe)
        int pn = lpos + (r + 2) * 256;
        eeB = (pn < cnt) ? csrP[base + pn] : SENTE;
        F1_CONSUME(uA, dlA);                    // chunk r
        #pragma unroll
        for (int g = 0; g < 8; ++g) { uA[g] = uN[g]; dlA[g] = dlN[g]; }
    }
    __syncthreads();

    // MFMA + epilogue: each wave handles 2 sub-tiles of 16 nodes.
    int mm = lane & 15, kq = lane >> 4;
    for (int i = 0; i < 2; ++i) {
        int st = wave * 2 + i;
        int row = st * 16 + mm;
        float dis = ((row < nlocal) ? dinv[node0 + row] : 0.f) * YINV;
        const int* ap = &acci[row * RSTRIDE];
        half8 A0, A1;
        #pragma unroll
        for (int j = 0; j < 8; ++j) {
            A0[j] = (_Float16)(dis * (float)ap[kq * 9 + j]);
            A1[j] = (_Float16)(dis * (float)ap[(4 + kq) * 9 + j]);
        }
        f32x4 acc[8];
        #pragma unroll
        for (int cb = 0; cb < 8; ++cb) acc[cb] = (f32x4){0.f, 0.f, 0.f, 0.f};
        #pragma unroll
        for (int cb = 0; cb < 8; ++cb) {
            half8 bh0 = as_half8(Wpk[(cb * 2 + 0) * 64 + lane]);
            half8 bh1 = as_half8(Wpk[(cb * 2 + 1) * 64 + lane]);
            half8 bl0 = as_half8(Wpk[1024 + (cb * 2 + 0) * 64 + lane]);
            half8 bl1 = as_half8(Wpk[1024 + (cb * 2 + 1) * 64 + lane]);
            acc[cb] = __builtin_amdgcn_mfma_f32_16x16x32_f16(A0, bh0, acc[cb], 0, 0, 0);
            acc[cb] = __builtin_amdgcn_mfma_f32_16x16x32_f16(A1, bh1, acc[cb], 0, 0, 0);
            acc[cb] = __builtin_amdgcn_mfma_f32_16x16x32_f16(A0, bl0, acc[cb], 0, 0, 0);
            acc[cb] = __builtin_amdgcn_mfma_f32_16x16x32_f16(A1, bl1, acc[cb], 0, 0, 0);
        }
        float zp[4] = {0.f, 0.f, 0.f, 0.f};
        #pragma unroll
        for (int cb = 0; cb < 8; ++cb) {
            int colg = cb * 16 + mm;
            float bb1 = b1[colg], vv = v[colg];
            #pragma unroll
            for (int rr = 0; rr < 4; ++rr) {
                float h = acc[cb][rr] + bb1;
                h = fmaxf(h, 0.f);
                zp[rr] += h * vv;
            }
        }
        #pragma unroll
        for (int off = 1; off < 16; off <<= 1) {
            #pragma unroll
            for (int rr = 0; rr < 4; ++rr) zp[rr] += __shfl_xor(zp[rr], off, 64);
        }
        if (mm == 0) {
            int nb = st * 16 + kq * 4;
            #pragma unroll
            for (int rr = 0; rr < 4; ++rr)
                if (nb + rr < nlocal)
                    zz[node0 + nb + rr] = dinv[node0 + nb + rr] * zp[rr];
        }
    }
}

// Layer 2 (collapsed): per-bucket tile-major zz gather (L1/L2 window) +
// int fixed-point LDS accumulate. out[i] = c + dinv[i]*(zz[i] + sum_in zz[s]).
__global__ __launch_bounds__(256) void out_kernel(
    const int* __restrict__ bcnt, const unsigned int* __restrict__ csrP,
    const float* __restrict__ dinv, const float* __restrict__ zz,
    const float* __restrict__ c, float* __restrict__ out, int n) {
    __shared__ int acc2[BNODES];
    int b = blockIdx.x, t = threadIdx.x;
    int node0 = b << BSHIFT;
    int nlocal = min(BNODES, n - node0);
    int base = b * SCAP;
    int cnt = bcnt[b];
    if (t < BNODES) acc2[t] = 0;
    __syncthreads();
    for (int idx = t; idx < cnt; idx += 256) {
        unsigned int e = csrP[base + idx];
        float z = zz[e >> BSHIFT];
        atomicAdd(&acc2[e & (BNODES - 1)], __float2int_rn(z * ZSCALE));
    }
    __syncthreads();
    if (t < nlocal) {
        int node = node0 + t;
        out[node] = c[0] + dinv[node] * ((float)acc2[t] * ZINV + zz[node]);
    }
}

extern "C" void kernel_launch(void* const* d_in, const int* in_sizes, int n_in,
                              void* d_out, int out_size, void* d_ws, size_t ws_size,
                              hipStream_t stream) {
    const float* x  = (const float*)d_in[0];
    const int*   ei = (const int*)d_in[1];
    const float* W1 = (const float*)d_in[2];
    const float* b1 = (const float*)d_in[3];
    const float* W2 = (const float*)d_in[4];
    const float* b2 = (const float*)d_in[5];
    const float* Wl = (const float*)d_in[6];
    const float* bl = (const float*)d_in[7];
    float* out = (float*)d_out;

    int E = in_sizes[1] / 2;
    const int* src = ei;
    const int* dst = ei + E;

    float* ws      = (float*)d_ws;
    float* dinv    = ws;                        // 100000
    float* zz      = dinv + N_NODES;            // 100000
    float* v       = zz + N_NODES;              // 128
    float* c       = v + HID;                   // 4
    int*   bcur2   = (int*)(c + 4);             // 12512 bin cursors
    int*   bcnt    = bcur2 + NBINS;             // 784 (padded for alignment)
    int*   csrP    = bcnt + 784;                // NBUCKETS*SCAP = 2001920
    uint4* Wpk     = (uint4*)(csrP + (size_t)NBUCKETS * SCAP);  // 2048 uint4
    int*   buf     = (int*)((float*)Wpk + 8192);  // bins then y: NBUCKETS*4096 ints

    int nchunks = (E + ACHUNK - 1) / ACHUNK;   // 391

    prep_kernel<<<9, 256, 0, stream>>>(W1, W2, b2, Wl, bl, v, c, Wpk, bcur2);
    scatter_kernel<<<nchunks, 256, 0, stream>>>(src, dst, bcur2, buf, E);
    compact_kernel<<<NBUCKETS, 256, 0, stream>>>(
        bcur2, buf, (unsigned int*)csrP, bcnt, dinv, (const float4*)x, N_NODES);
    fused1_kernel<<<NBUCKETS, 256, 0, stream>>>(
        (const int4*)buf, (const short*)buf, (const unsigned int*)csrP,
        bcnt, dinv, Wpk, b1, v, zz, N_NODES);
    out_kernel<<<NBUCKETS, 256, 0, stream>>>(
        bcnt, (const unsigned int*)csrP, dinv, zz, c, out, N_NODES);
}

// Round 7
// 182.399 us; speedup vs baseline: 1.3385x; 1.3385x over previous
//
#include <hip/hip_runtime.h>
#include <hip/hip_fp16.h>

// GCN 2-layer, N=100000, F=64, H=128, O=100, out [N,1] fp32.
// out = agg(relu(agg(x)@W1 + b1) . (W2@Wl)) + (b2@Wl + bl)
// r7 pipeline (r5 structure + r6 fused1 + merged prep):
//  memset:  bcur[782] = 0 (offset-based cursors).
//  partA:   blocks [0,nchunks): LDS multi-split of 4096 edges into padded
//           dst-buckets (ONE reserve-atomic per bucket per block, staged
//           run-length writes — the r6 direct scatter cost 85us in 64B-granule
//           HBM writes + serialized bin atomics; this structure is why).
//           blocks [nchunks, nchunks+9): prep (pack W1 fp16 hi+lo, v=W2@Wl,
//           c=b2.Wl+bl, zero-row y[N]).
//  partB:   per bucket: dl-histogram -> dinv; 13-bin TILE-major counting sort
//           (tile = src>>13 = 1MB of y); emits int16 (2^12) dinv-prescaled y.
//  fused1:  782 blocks all-resident (4/CU); tile-order gather keeps live y-tile
//           L2-hot per XCD (verified 60-64MB fetch r4-r6); 2-deep pipelined
//           8-edge x 8-col gather; invalid slots redirect to zero-row y[N];
//           int16 sext -> native ds_add_u32 into stride-77 LDS (13*dl mod 32
//           spans all 32 banks -> ~2-way, free). MFMA + fused L2-weight epilogue.
//  out:     per-bucket tile-major zz gather + native int LDS accumulate.
// fp32 LDS atomicAdd is a ~440cyc CAS loop on this toolchain (r1-r3);
// everything accumulates in int fixed-point (native ds_add_u32).

#define N_NODES 100000
#define F_IN 64
#define HID 128
#define OUT2 100
#define BSHIFT 7
#define BNODES 128
#define NBUCKETS ((N_NODES + BNODES - 1) / BNODES)  // 782
#define SCAP 2560   // bucket capacity: mean 2046 + ~11 sigma
#define ACHUNK 4096 // edges per partA block
#define NB_PAD 1024
#define SENTB 0xFFFFu
#define SENTE 0xFFFFFFFFu
#define TSHIFT 13   // src tile = src >> 13 (8192 srcs = 1 MB of y per tile)
#define NTILES 13   // ceil(100000 / 8192)
#define RSTRIDE 77  // acci ints per node row: odd -> 13*dl mod 32 spans 32 banks
#define ZROW N_NODES          // zero y-row for invalid gather slots
#define YSCALE 4096.0f        // y int16 fixed-point 2^12
#define YINV   (1.0f / 4096.0f)
#define ZSCALE 8192.0f        // zz accumulation fixed-point 2^13
#define ZINV   (1.0f / 8192.0f)

typedef _Float16 half8 __attribute__((ext_vector_type(8)));
typedef float f32x4 __attribute__((ext_vector_type(4)));

static __device__ __forceinline__ half8 as_half8(uint4 u) {
    union { uint4 u; half8 h; } x; x.u = u; return x.h;
}

// Pass A (+prep): edge blocks do LDS multi-split into padded dst-buckets;
// prep blocks pack W1 / v / c / zero-row. bcur holds per-bucket COUNTS
// (memset to 0 before launch); reserve = base + atomicAdd(count).
__global__ __launch_bounds__(256) void partA_kernel(
    const int* __restrict__ src, const int* __restrict__ dst,
    int* __restrict__ bcur, unsigned int* __restrict__ ebuf, int E, int nchunks,
    const float* __restrict__ W1, const float* __restrict__ W2,
    const float* __restrict__ b2, const float* __restrict__ Wl,
    const float* __restrict__ bl,
    float* __restrict__ v, float* __restrict__ c, uint4* __restrict__ Wpk,
    int* __restrict__ yzero) {
    int t = threadIdx.x;
    if ((int)blockIdx.x >= nchunks) {
        int pb = (int)blockIdx.x - nchunks;
        if (pb < 8) {
            // idx: bit10 = part (0=hi,1=lo), bits9..7 = cb, bit6 = kf, bits5..0 = lane
            int idx = pb * 256 + t;
            int lane2 = idx & 63;
            int kf    = (idx >> 6) & 1;
            int cb    = (idx >> 7) & 7;
            int part  = (idx >> 10) & 1;
            union { uint4 u; unsigned short s[8]; } pk;
            #pragma unroll
            for (int j = 0; j < 8; ++j) {
                int k    = kf * 32 + (lane2 >> 4) * 8 + j;
                int colg = cb * 16 + (lane2 & 15);
                float w = W1[k * HID + colg];
                __half h = __float2half_rn(w);
                if (part) h = __float2half_rn(w - __half2float(h));
                pk.s[j] = __half_as_ushort(h);
            }
            Wpk[idx] = pk.u;
        } else {
            if (t < HID) {
                float acc = 0.f;
                for (int k = 0; k < OUT2; ++k) acc += W2[t * OUT2 + k] * Wl[k];
                v[t] = acc;
            } else if (t == HID) {
                float acc = bl[0];
                for (int k = 0; k < OUT2; ++k) acc += b2[k] * Wl[k];
                *c = acc;
            }
            if (t < 128) yzero[t] = 0;   // 4 zero rows (int16) at y[N..N+3]
        }
        return;
    }
    __shared__ unsigned int stage[ACHUNK];       // 16 KB
    __shared__ unsigned short sb[ACHUNK];        // 8 KB
    __shared__ int hist[NB_PAD];                 // 4 KB each
    __shared__ int ocnt[NB_PAD];
    __shared__ int gbase[NB_PAD];
    __shared__ int cnt2[NB_PAD];
    int base = blockIdx.x * ACHUNK;
    int total = E - base; if (total > ACHUNK) total = ACHUNK;

    #pragma unroll
    for (int i = 0; i < 4; ++i) { hist[t + i * 256] = 0; cnt2[t + i * 256] = 0; }
    __syncthreads();

    unsigned int pe[16];
    unsigned short bk[16];
    #pragma unroll
    for (int k = 0; k < 16; ++k) {
        int e = base + k * 256 + t;
        if (e < E) {
            int s = src[e], d = dst[e];
            pe[k] = ((unsigned int)s << BSHIFT) | (unsigned int)(d & (BNODES - 1));
            bk[k] = (unsigned short)(d >> BSHIFT);
            atomicAdd(&hist[bk[k]], 1);
        } else {
            bk[k] = SENTB;
        }
    }
    __syncthreads();
    #pragma unroll
    for (int i = 0; i < 4; ++i) ocnt[t + i * 256] = hist[t + i * 256];
    __syncthreads();
    for (int off = 1; off < NB_PAD; off <<= 1) {
        int v4[4];
        #pragma unroll
        for (int i = 0; i < 4; ++i) {
            int p = t + i * 256;
            v4[i] = (p >= off) ? hist[p - off] : 0;
        }
        __syncthreads();
        #pragma unroll
        for (int i = 0; i < 4; ++i) hist[t + i * 256] += v4[i];
        __syncthreads();
    }
    #pragma unroll
    for (int i = 0; i < 4; ++i) {
        int b = (t + i * 256 + blockIdx.x * 131) & (NB_PAD - 1);
        int cc = ocnt[b];
        if (cc > 0 && b < NBUCKETS)
            gbase[b] = b * SCAP + atomicAdd(&bcur[b], cc);
    }
    __syncthreads();
    #pragma unroll
    for (int k = 0; k < 16; ++k) {
        if (bk[k] != SENTB) {
            int b = bk[k];
            int pos = (hist[b] - ocnt[b]) + atomicAdd(&cnt2[b], 1);
            stage[pos] = pe[k];
            sb[pos] = (unsigned short)b;
        }
    }
    __syncthreads();
    #pragma unroll
    for (int k = 0; k < 16; ++k) {
        int idx = k * 256 + t;
        if (idx < total) {
            int b = sb[idx];
            int lo = hist[b] - ocnt[b];
            ebuf[gbase[b] + (idx - lo)] = stage[idx];
        }
    }
}

// Pass B: per bucket: dl-histogram -> dinv; 13-bin TILE-major counting sort
// (in-place, full entries src<<7|dl); emits int16 (2^12) pre-scaled y rows.
__global__ __launch_bounds__(256) void partB_kernel(
    const int* __restrict__ bcur, unsigned int* __restrict__ csr,
    float* __restrict__ dinv,
    const float4* __restrict__ x4, uint2* __restrict__ y2, int n) {
    __shared__ int lcnt[BNODES];
    __shared__ float sdinv[BNODES];
    __shared__ int tcnt[16];
    __shared__ int tcur[16];
    __shared__ unsigned int sbuf[SCAP];      // 10 KB
    int b = blockIdx.x, t = threadIdx.x;
    int node0 = b << BSHIFT;
    int nlocal = min(BNODES, n - node0);
    int base = b * SCAP;
    int cnt = bcur[b];
    if (t < BNODES) lcnt[t] = 0;
    if (t < 16) tcnt[t] = 0;
    __syncthreads();
    unsigned int er[SCAP / 256];
    #pragma unroll
    for (int k = 0; k < SCAP / 256; ++k) {
        int idx = k * 256 + t;
        er[k] = (idx < cnt) ? csr[base + idx] : SENTE;
        if (er[k] != SENTE) {
            atomicAdd(&lcnt[er[k] & (BNODES - 1)], 1);
            atomicAdd(&tcnt[er[k] >> (BSHIFT + TSHIFT)], 1);
        }
    }
    __syncthreads();
    if (t < BNODES) {
        float sd = rsqrtf((float)lcnt[t] + 1.0f);
        sdinv[t] = sd;
        if (t < nlocal) dinv[node0 + t] = sd;
    }
    if (t == 0) {
        int s = 0;
        #pragma unroll
        for (int i = 0; i < NTILES; ++i) { tcur[i] = s; s += tcnt[i]; }
    }
    __syncthreads();
    #pragma unroll
    for (int k = 0; k < SCAP / 256; ++k) {
        unsigned int e = er[k];
        if (e != SENTE) {
            int p = atomicAdd(&tcur[e >> (BSHIFT + TSHIFT)], 1);
            sbuf[p] = e;
        }
    }
    __syncthreads();
    for (int idx = t; idx < cnt; idx += 256) csr[base + idx] = sbuf[idx];
    // y emission: int16 fixed-point, dinv[src]-prescaled
    for (int i = t; i < nlocal * 16; i += 256) {
        int nl = i >> 4;
        int gi = (node0 + nl) * 16 + (i & 15);
        float sc = sdinv[nl] * YSCALE;
        float4 xv = x4[gi];
        int a0 = __float2int_rn(xv.x * sc);
        int a1 = __float2int_rn(xv.y * sc);
        int a2 = __float2int_rn(xv.z * sc);
        int a3 = __float2int_rn(xv.w * sc);
        uint2 pk;
        pk.x = ((unsigned int)a0 & 0xFFFFu) | ((unsigned int)a1 << 16);
        pk.y = ((unsigned int)a2 & 0xFFFFu) | ((unsigned int)a3 << 16);
        y2[gi] = pk;
    }
}

// Fused layer 1: block = bucket (128 dst nodes), 782 blocks, 4/CU all resident.
// csr is tile-major -> live 1MB y-tile stays L2-hot per XCD.
// Gather: 64 lanes = 8 edges (q=lane>>3) x 8 int4 cols (col=lane&7); 2 chunks
// software-pipelined; invalid slots read the zero-row y[N] (no cndmask chain).
// int16 sext -> ds_add_u32 into stride-77 acci (13*dl mod 32 -> all 32 banks).
#define F1_ISSUE(EE, U, DL)                                            \
    _Pragma("unroll")                                                  \
    for (int g = 0; g < 8; ++g) {                                      \
        unsigned int e_ = __shfl((EE), g * 8 + q, 64);                 \
        int srow_ = (e_ != SENTE) ? (int)(e_ >> BSHIFT) : ZROW;        \
        DL[g] = (int)(e_ & (BNODES - 1));                              \
        U[g] = y4[srow_ * 8 + col];                                    \
    }

#define F1_CONSUME(U, DL)                                              \
    _Pragma("unroll")                                                  \
    for (int g = 0; g < 8; ++g) {                                      \
        int* rowp_ = &acci[DL[g] * RSTRIDE + col * 9];                 \
        const int* up_ = (const int*)&U[g];                            \
        _Pragma("unroll")                                              \
        for (int j = 0; j < 4; ++j) {                                  \
            int d_ = up_[j];                                           \
            atomicAdd(&rowp_[2 * j],     (d_ << 16) >> 16);            \
            atomicAdd(&rowp_[2 * j + 1], d_ >> 16);                    \
        }                                                              \
    }

__global__ __launch_bounds__(256, 4) void fused1_kernel(
    const int4* __restrict__ y4, const short* __restrict__ yh,
    const unsigned int* __restrict__ csr, const int* __restrict__ bcur,
    const float* __restrict__ dinv, const uint4* __restrict__ Wpk,
    const float* __restrict__ b1, const float* __restrict__ v,
    float* __restrict__ zz, int n) {
    __shared__ int acci[BNODES * RSTRIDE];   // 39424 B -> 4 blocks/CU
    int t = threadIdx.x;
    int lane = t & 63, wave = t >> 6;
    int q = lane >> 3, col = lane & 7;
    int b = blockIdx.x;
    int node0 = b << BSHIFT;
    int nlocal = min(BNODES, n - node0);
    int base = b * SCAP;
    int cnt = bcur[b];

    // self-loop init: acc[r][f] = y[node0+r][f] (int16, already dinv-prescaled)
    for (int r = wave; r < BNODES; r += 4) {
        int vv = 0;
        if (r < nlocal) vv = (int)yh[(node0 + r) * 64 + lane];
        acci[r * RSTRIDE + (lane >> 3) * 9 + (lane & 7)] = vv;
    }
    __syncthreads();

    // 2-deep pipelined edge accumulation in tile order
    int nr = (cnt + 255) >> 8;
    int lpos = wave * 64 + lane;
    unsigned int eeA = (lpos < cnt) ? csr[base + lpos] : SENTE;
    int4 uA[8]; int dlA[8];
    F1_ISSUE(eeA, uA, dlA);
    unsigned int eeB = (lpos + 256 < cnt) ? csr[base + lpos + 256] : SENTE;
    #pragma unroll 2
    for (int r = 0; r < nr; ++r) {
        int4 uN[8]; int dlN[8];
        F1_ISSUE(eeB, uN, dlN);                 // chunk r+1 (sentinel-safe)
        int pn = lpos + (r + 2) * 256;
        eeB = (pn < cnt) ? csr[base + pn] : SENTE;
        F1_CONSUME(uA, dlA);                    // chunk r
        #pragma unroll
        for (int g = 0; g < 8; ++g) { uA[g] = uN[g]; dlA[g] = dlN[g]; }
    }
    __syncthreads();

    // MFMA + epilogue: each wave handles 2 sub-tiles of 16 nodes.
    int mm = lane & 15, kq = lane >> 4;
    for (int i = 0; i < 2; ++i) {
        int st = wave * 2 + i;
        int row = st * 16 + mm;
        float dis = ((row < nlocal) ? dinv[node0 + row] : 0.f) * YINV;
        const int* ap = &acci[row * RSTRIDE];
        half8 A0, A1;
        #pragma unroll
        for (int j = 0; j < 8; ++j) {
            A0[j] = (_Float16)(dis * (float)ap[kq * 9 + j]);
            A1[j] = (_Float16)(dis * (float)ap[(4 + kq) * 9 + j]);
        }
        f32x4 acc[8];
        #pragma unroll
        for (int cb = 0; cb < 8; ++cb) acc[cb] = (f32x4){0.f, 0.f, 0.f, 0.f};
        #pragma unroll
        for (int cb = 0; cb < 8; ++cb) {
            half8 bh0 = as_half8(Wpk[(cb * 2 + 0) * 64 + lane]);
            half8 bh1 = as_half8(Wpk[(cb * 2 + 1) * 64 + lane]);
            half8 bl0 = as_half8(Wpk[1024 + (cb * 2 + 0) * 64 + lane]);
            half8 bl1 = as_half8(Wpk[1024 + (cb * 2 + 1) * 64 + lane]);
            acc[cb] = __builtin_amdgcn_mfma_f32_16x16x32_f16(A0, bh0, acc[cb], 0, 0, 0);
            acc[cb] = __builtin_amdgcn_mfma_f32_16x16x32_f16(A1, bh1, acc[cb], 0, 0, 0);
            acc[cb] = __builtin_amdgcn_mfma_f32_16x16x32_f16(A0, bl0, acc[cb], 0, 0, 0);
            acc[cb] = __builtin_amdgcn_mfma_f32_16x16x32_f16(A1, bl1, acc[cb], 0, 0, 0);
        }
        float zp[4] = {0.f, 0.f, 0.f, 0.f};
        #pragma unroll
        for (int cb = 0; cb < 8; ++cb) {
            int colg = cb * 16 + mm;
            float bb1 = b1[colg], vv = v[colg];
            #pragma unroll
            for (int rr = 0; rr < 4; ++rr) {
                float h = acc[cb][rr] + bb1;
                h = fmaxf(h, 0.f);
                zp[rr] += h * vv;
            }
        }
        #pragma unroll
        for (int off = 1; off < 16; off <<= 1) {
            #pragma unroll
            for (int rr = 0; rr < 4; ++rr) zp[rr] += __shfl_xor(zp[rr], off, 64);
        }
        if (mm == 0) {
            int nb = st * 16 + kq * 4;
            #pragma unroll
            for (int rr = 0; rr < 4; ++rr)
                if (nb + rr < nlocal)
                    zz[node0 + nb + rr] = dinv[node0 + nb + rr] * zp[rr];
        }
    }
}

// Layer 2 (collapsed): per-bucket tile-major zz gather (L1/L2 window) +
// int fixed-point LDS accumulate. out[i] = c + dinv[i]*(zz[i] + sum_in zz[s]).
__global__ __launch_bounds__(256) void out_kernel(
    const int* __restrict__ bcur, const unsigned int* __restrict__ csr,
    const float* __restrict__ dinv, const float* __restrict__ zz,
    const float* __restrict__ c, float* __restrict__ out, int n) {
    __shared__ int acc2[BNODES];
    int b = blockIdx.x, t = threadIdx.x;
    int node0 = b << BSHIFT;
    int nlocal = min(BNODES, n - node0);
    int base = b * SCAP;
    int cnt = bcur[b];
    if (t < BNODES) acc2[t] = 0;
    __syncthreads();
    for (int idx = t; idx < cnt; idx += 256) {
        unsigned int e = csr[base + idx];
        float z = zz[e >> BSHIFT];
        atomicAdd(&acc2[e & (BNODES - 1)], __float2int_rn(z * ZSCALE));
    }
    __syncthreads();
    if (t < nlocal) {
        int node = node0 + t;
        out[node] = c[0] + dinv[node] * ((float)acc2[t] * ZINV + zz[node]);
    }
}

extern "C" void kernel_launch(void* const* d_in, const int* in_sizes, int n_in,
                              void* d_out, int out_size, void* d_ws, size_t ws_size,
                              hipStream_t stream) {
    const float* x  = (const float*)d_in[0];
    const int*   ei = (const int*)d_in[1];
    const float* W1 = (const float*)d_in[2];
    const float* b1 = (const float*)d_in[3];
    const float* W2 = (const float*)d_in[4];
    const float* b2 = (const float*)d_in[5];
    const float* Wl = (const float*)d_in[6];
    const float* bl = (const float*)d_in[7];
    float* out = (float*)d_out;

    int E = in_sizes[1] / 2;
    const int* src = ei;
    const int* dst = ei + E;

    float* ws      = (float*)d_ws;
    float* dinv    = ws;                        // 100000
    float* zz      = dinv + N_NODES;            // 100000
    float* v       = zz + N_NODES;              // 128
    float* c       = v + HID;                   // 4
    int*   bcur    = (int*)(c + 4);             // 782 counts (+pad to 1024)
    int*   csr     = bcur + NB_PAD;             // NBUCKETS*SCAP ints
    uint4* Wpk     = (uint4*)(csr + (size_t)NBUCKETS * SCAP);  // 2048 uint4
    short* y       = (short*)((float*)Wpk + 8192);  // (N+4)*64 int16

    int nchunks = (E + ACHUNK - 1) / ACHUNK;   // 391

    hipMemsetAsync(bcur, 0, NBUCKETS * sizeof(int), stream);
    partA_kernel<<<nchunks + 9, 256, 0, stream>>>(
        src, dst, bcur, (unsigned int*)csr, E, nchunks,
        W1, W2, b2, Wl, bl, v, c, Wpk, (int*)(y + (size_t)ZROW * 64));
    partB_kernel<<<NBUCKETS, 256, 0, stream>>>(
        bcur, (unsigned int*)csr, dinv, (const float4*)x, (uint2*)y, N_NODES);
    fused1_kernel<<<NBUCKETS, 256, 0, stream>>>(
        (const int4*)y, (const short*)y, (const unsigned int*)csr,
        bcur, dinv, Wpk, b1, v, zz, N_NODES);
    out_kernel<<<NBUCKETS, 256, 0, stream>>>(
        bcur, (const unsigned int*)csr, dinv, zz, c, out, N_NODES);
}

// Round 8
// 179.211 us; speedup vs baseline: 1.3623x; 1.0178x over previous
//
#include <hip/hip_runtime.h>
#include <hip/hip_fp16.h>

// GCN 2-layer, N=100000, F=64, H=128, O=100, out [N,1] fp32.
// out = agg(relu(agg(x)@W1 + b1) . (W2@Wl)) + (b2@Wl + bl)
// r8: BNODES 64 (grid 1563) to double fused1 occupancy — r7 showed fused1's
// gather BW is grid-size-limited (782 blocks = 3/CU = 23% occ = 1.3-1.8 TB/s
// vs 2.35 TB/s the same pattern hits at higher occ). 1-deep pipeline restored
// (r7's 2-deep widened the live tile window past the 4MB XCD L2: fetch 64->99MB).
//  memset: bcur[1563] = 0.
//  partA:  blocks [0,nchunks): LDS multi-split of 4096 edges into padded
//          dst-buckets (ONE reserve-atomic per bucket per block, staged
//          run-length writes). blocks [nchunks,+9): prep (W1 fp16 hi+lo pack,
//          v=W2@Wl, c=b2.Wl+bl, zero y-row).
//  partB:  per bucket: dl-histogram -> dinv; 13-bin TILE-major counting sort
//          (tile = src>>13 = 1MB of y); emits int16 (2^12) dinv-prescaled y.
//  fused1: 1563 blocks (~6/CU, launch_bounds(256,6), 19.7KB LDS); tile-order
//          gather keeps live y-tile L2-hot per XCD; 8-edge x 8-col gather,
//          1-deep prefetch; invalid slots read zero-row y[N]; int16 sext ->
//          native ds_add_u32 into stride-77 acci. MFMA + fused L2-weight epi.
//  out:    per-bucket tile-major zz gather + native int LDS accumulate.
// fp32 LDS atomicAdd is a ~440cyc CAS loop on this toolchain (r1-r3);
// everything accumulates in int fixed-point (native ds_add_u32).

#define N_NODES 100000
#define F_IN 64
#define HID 128
#define OUT2 100
#define BSHIFT 6
#define BNODES 64
#define NBUCKETS ((N_NODES + BNODES - 1) / BNODES)  // 1563
#define SCAP 1408   // bucket capacity: mean 1024 + 12 sigma (sigma=32)
#define ACHUNK 4096 // edges per partA block
#define NB_PAD 2048
#define SENTB 0xFFFFu
#define SENTE 0xFFFFFFFFu
#define TSHIFT 13   // src tile = src >> 13 (8192 srcs = 1 MB of y per tile)
#define NTILES 13   // ceil(100000 / 8192)
#define RSTRIDE 77  // acci ints per node row: 8 blocks x 9 + pad (odd stride)
#define ZROW N_NODES          // zero y-row for invalid gather slots
#define YSCALE 4096.0f        // y int16 fixed-point 2^12
#define YINV   (1.0f / 4096.0f)
#define ZSCALE 8192.0f        // zz accumulation fixed-point 2^13
#define ZINV   (1.0f / 8192.0f)

typedef _Float16 half8 __attribute__((ext_vector_type(8)));
typedef float f32x4 __attribute__((ext_vector_type(4)));

static __device__ __forceinline__ half8 as_half8(uint4 u) {
    union { uint4 u; half8 h; } x; x.u = u; return x.h;
}

// Pass A (+prep): edge blocks LDS-multisplit into padded dst-buckets;
// prep blocks pack W1 / v / c / zero-row. bcur = per-bucket COUNTS
// (memset 0 before launch); reserve = b*SCAP + atomicAdd(count).
__global__ __launch_bounds__(256) void partA_kernel(
    const int* __restrict__ src, const int* __restrict__ dst,
    int* __restrict__ bcur, unsigned int* __restrict__ ebuf, int E, int nchunks,
    const float* __restrict__ W1, const float* __restrict__ W2,
    const float* __restrict__ b2, const float* __restrict__ Wl,
    const float* __restrict__ bl,
    float* __restrict__ v, float* __restrict__ c, uint4* __restrict__ Wpk,
    int* __restrict__ yzero) {
    int t = threadIdx.x;
    if ((int)blockIdx.x >= nchunks) {
        int pb = (int)blockIdx.x - nchunks;
        if (pb < 8) {
            // idx: bit10 = part (0=hi,1=lo), bits9..7 = cb, bit6 = kf, bits5..0 = lane
            int idx = pb * 256 + t;
            int lane2 = idx & 63;
            int kf    = (idx >> 6) & 1;
            int cb    = (idx >> 7) & 7;
            int part  = (idx >> 10) & 1;
            union { uint4 u; unsigned short s[8]; } pk;
            #pragma unroll
            for (int j = 0; j < 8; ++j) {
                int k    = kf * 32 + (lane2 >> 4) * 8 + j;
                int colg = cb * 16 + (lane2 & 15);
                float w = W1[k * HID + colg];
                __half h = __float2half_rn(w);
                if (part) h = __float2half_rn(w - __half2float(h));
                pk.s[j] = __half_as_ushort(h);
            }
            Wpk[idx] = pk.u;
        } else {
            if (t < HID) {
                float acc = 0.f;
                for (int k = 0; k < OUT2; ++k) acc += W2[t * OUT2 + k] * Wl[k];
                v[t] = acc;
            } else if (t == HID) {
                float acc = bl[0];
                for (int k = 0; k < OUT2; ++k) acc += b2[k] * Wl[k];
                *c = acc;
            }
            if (t < 128) yzero[t] = 0;   // zero rows (int16) at y[N..]
        }
        return;
    }
    __shared__ unsigned int stage[ACHUNK];       // 16 KB
    __shared__ unsigned short sb[ACHUNK];        // 8 KB
    __shared__ int hist[NB_PAD];                 // 8 KB each
    __shared__ int ocnt[NB_PAD];
    __shared__ int gbase[NB_PAD];
    __shared__ int cnt2[NB_PAD];
    int base = blockIdx.x * ACHUNK;
    int total = E - base; if (total > ACHUNK) total = ACHUNK;

    #pragma unroll
    for (int i = 0; i < 8; ++i) { hist[t + i * 256] = 0; cnt2[t + i * 256] = 0; }
    __syncthreads();

    unsigned int pe[16];
    unsigned short bk[16];
    #pragma unroll
    for (int k = 0; k < 16; ++k) {
        int e = base + k * 256 + t;
        if (e < E) {
            int s = src[e], d = dst[e];
            pe[k] = ((unsigned int)s << BSHIFT) | (unsigned int)(d & (BNODES - 1));
            bk[k] = (unsigned short)(d >> BSHIFT);
            atomicAdd(&hist[bk[k]], 1);
        } else {
            bk[k] = SENTB;
        }
    }
    __syncthreads();
    #pragma unroll
    for (int i = 0; i < 8; ++i) ocnt[t + i * 256] = hist[t + i * 256];
    __syncthreads();
    for (int off = 1; off < NB_PAD; off <<= 1) {
        int v8[8];
        #pragma unroll
        for (int i = 0; i < 8; ++i) {
            int p = t + i * 256;
            v8[i] = (p >= off) ? hist[p - off] : 0;
        }
        __syncthreads();
        #pragma unroll
        for (int i = 0; i < 8; ++i) hist[t + i * 256] += v8[i];
        __syncthreads();
    }
    #pragma unroll
    for (int i = 0; i < 8; ++i) {
        int b = (t + i * 256 + blockIdx.x * 131) & (NB_PAD - 1);
        int cc = ocnt[b];
        if (cc > 0 && b < NBUCKETS)
            gbase[b] = b * SCAP + atomicAdd(&bcur[b], cc);
    }
    __syncthreads();
    #pragma unroll
    for (int k = 0; k < 16; ++k) {
        if (bk[k] != SENTB) {
            int b = bk[k];
            int pos = (hist[b] - ocnt[b]) + atomicAdd(&cnt2[b], 1);
            stage[pos] = pe[k];
            sb[pos] = (unsigned short)b;
        }
    }
    __syncthreads();
    #pragma unroll
    for (int k = 0; k < 16; ++k) {
        int idx = k * 256 + t;
        if (idx < total) {
            int b = sb[idx];
            int lo = hist[b] - ocnt[b];
            ebuf[gbase[b] + (idx - lo)] = stage[idx];
        }
    }
}

// Pass B: per bucket: dl-histogram -> dinv; 13-bin TILE-major counting sort
// (in-place, full entries src<<6|dl); emits int16 (2^12) pre-scaled y rows.
__global__ __launch_bounds__(256) void partB_kernel(
    const int* __restrict__ bcur, unsigned int* __restrict__ csr,
    float* __restrict__ dinv,
    const float4* __restrict__ x4, uint2* __restrict__ y2, int n) {
    __shared__ int lcnt[BNODES];
    __shared__ float sdinv[BNODES];
    __shared__ int tcnt[16];
    __shared__ int tcur[16];
    __shared__ unsigned int sbuf[SCAP];      // 5.5 KB
    int b = blockIdx.x, t = threadIdx.x;
    int node0 = b << BSHIFT;
    int nlocal = min(BNODES, n - node0);
    int base = b * SCAP;
    int cnt = bcur[b];
    if (t < BNODES) lcnt[t] = 0;
    if (t < 16) tcnt[t] = 0;
    __syncthreads();
    unsigned int er[6];
    #pragma unroll
    for (int k = 0; k < 6; ++k) {
        int idx = k * 256 + t;
        er[k] = (idx < cnt) ? csr[base + idx] : SENTE;
        if (er[k] != SENTE) {
            atomicAdd(&lcnt[er[k] & (BNODES - 1)], 1);
            atomicAdd(&tcnt[er[k] >> (BSHIFT + TSHIFT)], 1);
        }
    }
    __syncthreads();
    if (t < BNODES) {
        float sd = rsqrtf((float)lcnt[t] + 1.0f);
        sdinv[t] = sd;
        if (t < nlocal) dinv[node0 + t] = sd;
    }
    if (t == 0) {
        int s = 0;
        #pragma unroll
        for (int i = 0; i < NTILES; ++i) { tcur[i] = s; s += tcnt[i]; }
    }
    __syncthreads();
    #pragma unroll
    for (int k = 0; k < 6; ++k) {
        unsigned int e = er[k];
        if (e != SENTE) {
            int p = atomicAdd(&tcur[e >> (BSHIFT + TSHIFT)], 1);
            sbuf[p] = e;
        }
    }
    __syncthreads();
    for (int idx = t; idx < cnt; idx += 256) csr[base + idx] = sbuf[idx];
    // y emission: int16 fixed-point, dinv[src]-prescaled
    for (int i = t; i < nlocal * 16; i += 256) {
        int nl = i >> 4;
        int gi = (node0 + nl) * 16 + (i & 15);
        float sc = sdinv[nl] * YSCALE;
        float4 xv = x4[gi];
        int a0 = __float2int_rn(xv.x * sc);
        int a1 = __float2int_rn(xv.y * sc);
        int a2 = __float2int_rn(xv.z * sc);
        int a3 = __float2int_rn(xv.w * sc);
        uint2 pk;
        pk.x = ((unsigned int)a0 & 0xFFFFu) | ((unsigned int)a1 << 16);
        pk.y = ((unsigned int)a2 & 0xFFFFu) | ((unsigned int)a3 << 16);
        y2[gi] = pk;
    }
}

// Fused layer 1: block = bucket (64 dst nodes), 1563 blocks (~6/CU).
// csr is tile-major -> live 1MB y-tile stays L2-hot per XCD.
// Gather: 64 lanes = 8 edges (q=lane>>3) x 8 int4 cols (col=lane&7); 1-deep
// csr prefetch; invalid slots read zero-row y[N]. int16 sext -> ds_add_u32.
#define F1_ISSUE(EE, U, DL)                                            \
    _Pragma("unroll")                                                  \
    for (int g = 0; g < 8; ++g) {                                      \
        unsigned int e_ = __shfl((EE), g * 8 + q, 64);                 \
        int srow_ = (e_ != SENTE) ? (int)(e_ >> BSHIFT) : ZROW;        \
        DL[g] = (int)(e_ & (BNODES - 1));                              \
        U[g] = y4[srow_ * 8 + col];                                    \
    }

#define F1_CONSUME(U, DL)                                              \
    _Pragma("unroll")                                                  \
    for (int g = 0; g < 8; ++g) {                                      \
        int* rowp_ = &acci[DL[g] * RSTRIDE + col * 9];                 \
        const int* up_ = (const int*)&U[g];                            \
        _Pragma("unroll")                                              \
        for (int j = 0; j < 4; ++j) {                                  \
            int d_ = up_[j];                                           \
            atomicAdd(&rowp_[2 * j],     (d_ << 16) >> 16);            \
            atomicAdd(&rowp_[2 * j + 1], d_ >> 16);                    \
        }                                                              \
    }

__global__ __launch_bounds__(256, 6) void fused1_kernel(
    const int4* __restrict__ y4, const short* __restrict__ yh,
    const unsigned int* __restrict__ csr, const int* __restrict__ bcur,
    const float* __restrict__ dinv, const uint4* __restrict__ Wpk,
    const float* __restrict__ b1, const float* __restrict__ v,
    float* __restrict__ zz, int n) {
    __shared__ int acci[BNODES * RSTRIDE];   // 19712 B -> up to 8 blocks/CU
    int t = threadIdx.x;
    int lane = t & 63, wave = t >> 6;
    int q = lane >> 3, col = lane & 7;
    int b = blockIdx.x;
    int node0 = b << BSHIFT;
    int nlocal = min(BNODES, n - node0);
    int base = b * SCAP;
    int cnt = bcur[b];

    // self-loop init: acc[r][f] = y[node0+r][f] (int16, already dinv-prescaled)
    for (int r = wave; r < BNODES; r += 4) {
        int vv = 0;
        if (r < nlocal) vv = (int)yh[(node0 + r) * 64 + lane];
        acci[r * RSTRIDE + q * 9 + col] = vv;
    }
    __syncthreads();

    // 1-deep pipelined edge accumulation in tile order (waves interleave
    // 64-edge chunks; per-block round = 256 edges keeps the live tile window
    // inside the per-XCD L2 — 2-deep blew fetch 64->99MB in r7).
    int nr = (cnt + 255) >> 8;
    int lpos = wave * 64 + lane;
    unsigned int ee = (lpos < cnt) ? csr[base + lpos] : SENTE;
    for (int r = 0; r < nr; ++r) {
        int pn = lpos + (r + 1) * 256;
        unsigned int een = (pn < cnt) ? csr[base + pn] : SENTE;
        int4 u[8]; int dl[8];
        F1_ISSUE(ee, u, dl);
        F1_CONSUME(u, dl);
        ee = een;
    }
    __syncthreads();

    // MFMA + epilogue: wave handles its one 16-node sub-tile.
    int mm = lane & 15, kq = lane >> 4;
    int st = wave;
    int row = st * 16 + mm;
    float dis = ((row < nlocal) ? dinv[node0 + row] : 0.f) * YINV;
    const int* ap = &acci[row * RSTRIDE];
    half8 A0, A1;
    #pragma unroll
    for (int j = 0; j < 8; ++j) {
        A0[j] = (_Float16)(dis * (float)ap[kq * 9 + j]);
        A1[j] = (_Float16)(dis * (float)ap[(4 + kq) * 9 + j]);
    }
    f32x4 acc[8];
    #pragma unroll
    for (int cb = 0; cb < 8; ++cb) acc[cb] = (f32x4){0.f, 0.f, 0.f, 0.f};
    #pragma unroll
    for (int cb = 0; cb < 8; ++cb) {
        half8 bh0 = as_half8(Wpk[(cb * 2 + 0) * 64 + lane]);
        half8 bh1 = as_half8(Wpk[(cb * 2 + 1) * 64 + lane]);
        half8 bl0 = as_half8(Wpk[1024 + (cb * 2 + 0) * 64 + lane]);
        half8 bl1 = as_half8(Wpk[1024 + (cb * 2 + 1) * 64 + lane]);
        acc[cb] = __builtin_amdgcn_mfma_f32_16x16x32_f16(A0, bh0, acc[cb], 0, 0, 0);
        acc[cb] = __builtin_amdgcn_mfma_f32_16x16x32_f16(A1, bh1, acc[cb], 0, 0, 0);
        acc[cb] = __builtin_amdgcn_mfma_f32_16x16x32_f16(A0, bl0, acc[cb], 0, 0, 0);
        acc[cb] = __builtin_amdgcn_mfma_f32_16x16x32_f16(A1, bl1, acc[cb], 0, 0, 0);
    }
    float zp[4] = {0.f, 0.f, 0.f, 0.f};
    #pragma unroll
    for (int cb = 0; cb < 8; ++cb) {
        int colg = cb * 16 + mm;
        float bb1 = b1[colg], vv = v[colg];
        #pragma unroll
        for (int rr = 0; rr < 4; ++rr) {
            float h = acc[cb][rr] + bb1;
            h = fmaxf(h, 0.f);
            zp[rr] += h * vv;
        }
    }
    #pragma unroll
    for (int off = 1; off < 16; off <<= 1) {
        #pragma unroll
        for (int rr = 0; rr < 4; ++rr) zp[rr] += __shfl_xor(zp[rr], off, 64);
    }
    if (mm == 0) {
        int nb = st * 16 + kq * 4;
        #pragma unroll
        for (int rr = 0; rr < 4; ++rr)
            if (nb + rr < nlocal)
                zz[node0 + nb + rr] = dinv[node0 + nb + rr] * zp[rr];
    }
}

// Layer 2 (collapsed): per-bucket tile-major zz gather (L1/L2 window) +
// native int LDS accumulate. out[i] = c + dinv[i]*(zz[i] + sum_in zz[s]).
__global__ __launch_bounds__(256) void out_kernel(
    const int* __restrict__ bcur, const unsigned int* __restrict__ csr,
    const float* __restrict__ dinv, const float* __restrict__ zz,
    const float* __restrict__ c, float* __restrict__ out, int n) {
    __shared__ int acc2[BNODES];
    int b = blockIdx.x, t = threadIdx.x;
    int node0 = b << BSHIFT;
    int nlocal = min(BNODES, n - node0);
    int base = b * SCAP;
    int cnt = bcur[b];
    if (t < BNODES) acc2[t] = 0;
    __syncthreads();
    for (int idx = t; idx < cnt; idx += 256) {
        unsigned int e = csr[base + idx];
        float z = zz[e >> BSHIFT];
        atomicAdd(&acc2[e & (BNODES - 1)], __float2int_rn(z * ZSCALE));
    }
    __syncthreads();
    if (t < nlocal) {
        int node = node0 + t;
        out[node] = c[0] + dinv[node] * ((float)acc2[t] * ZINV + zz[node]);
    }
}

extern "C" void kernel_launch(void* const* d_in, const int* in_sizes, int n_in,
                              void* d_out, int out_size, void* d_ws, size_t ws_size,
                              hipStream_t stream) {
    const float* x  = (const float*)d_in[0];
    const int*   ei = (const int*)d_in[1];
    const float* W1 = (const float*)d_in[2];
    const float* b1 = (const float*)d_in[3];
    const float* W2 = (const float*)d_in[4];
    const float* b2 = (const float*)d_in[5];
    const float* Wl = (const float*)d_in[6];
    const float* bl = (const float*)d_in[7];
    float* out = (float*)d_out;

    int E = in_sizes[1] / 2;
    const int* src = ei;
    const int* dst = ei + E;

    float* ws      = (float*)d_ws;
    float* dinv    = ws;                        // 100000
    float* zz      = dinv + N_NODES;            // 100000
    float* v       = zz + N_NODES;              // 128
    float* c       = v + HID;                   // 4
    int*   bcur    = (int*)(c + 4);             // 1563 counts (pad to 2048)
    int*   csr     = bcur + NB_PAD;             // NBUCKETS*SCAP = 2200704 ints
    uint4* Wpk     = (uint4*)(csr + (size_t)NBUCKETS * SCAP);  // 2048 uint4
    short* y       = (short*)((float*)Wpk + 8192);  // (N+4)*64 int16

    int nchunks = (E + ACHUNK - 1) / ACHUNK;   // 391

    hipMemsetAsync(bcur, 0, NBUCKETS * sizeof(int), stream);
    partA_kernel<<<nchunks + 9, 256, 0, stream>>>(
        src, dst, bcur, (unsigned int*)csr, E, nchunks,
        W1, W2, b2, Wl, bl, v, c, Wpk, (int*)(y + (size_t)ZROW * 64));
    partB_kernel<<<NBUCKETS, 256, 0, stream>>>(
        bcur, (unsigned int*)csr, dinv, (const float4*)x, (uint2*)y, N_NODES);
    fused1_kernel<<<NBUCKETS, 256, 0, stream>>>(
        (const int4*)y, (const short*)y, (const unsigned int*)csr,
        bcur, dinv, Wpk, b1, v, zz, N_NODES);
    out_kernel<<<NBUCKETS, 256, 0, stream>>>(
        bcur, (const unsigned int*)csr, dinv, zz, c, out, N_NODES);
}